// Round 4
// baseline (776.065 us; speedup 1.0000x reference)
//
#include <hip/hip_runtime.h>
#include <hip/hip_bf16.h>

#define N_NODES 100000
#define N_EDGES 3200000
#define F_IN 256
#define D_OUT 64
#define BATCH 4096
#define N_FIELDS 20
#define N_ENTRIES (BATCH * N_FIELDS)          // 81920
#define SCAN_B 512
#define N_SCAN_BLOCKS ((N_NODES + SCAN_B - 1) / SCAN_B)   // 196

static __device__ __forceinline__ float bfbits2f(unsigned short u) {
    return __uint_as_float((unsigned)u << 16);
}
static __device__ __forceinline__ unsigned short f2bf_bits(float x) {
    __hip_bfloat16 h = __float2bfloat16(x);
    return *reinterpret_cast<unsigned short*>(&h);
}

// ---- 0. dtype detector (insurance; expected to report f32) ----
// Tests the LOW 16 bits of each word: for bf16-pair data that's a true bf16
// exponent (in [90,160] w.p. ~1); for f32 data it's mantissa bits (~0.28).
__global__ void k_detect(const unsigned* __restrict__ featw, int* __restrict__ flag) {
    __shared__ int cnt;
    if (threadIdx.x == 0) cnt = 0;
    __syncthreads();
    int hits = 0;
#pragma unroll
    for (int j = 0; j < 4; j++) {
        unsigned w = featw[threadIdx.x * 4 + j];
        int ex = (w >> 7) & 0xff;
        if (ex >= 90 && ex <= 160) hits++;
    }
    atomicAdd(&cnt, hits);
    __syncthreads();
    if (threadIdx.x == 0) *flag = (cnt >= 768) ? 0 /*bf16*/ : 1 /*f32*/;
}

// ---- 1. degree count (in-degree over dst) ----
__global__ void k_count(const int* __restrict__ dst, int* __restrict__ counts) {
    int e = blockIdx.x * blockDim.x + threadIdx.x;
    if (e < N_EDGES) atomicAdd(&counts[dst[e]], 1);
}

// ---- 2a. per-block inclusive scan -> exclusive localScan + blockSums ----
__global__ void k_scan_local(const int* __restrict__ counts,
                             int* __restrict__ localScan,
                             int* __restrict__ blockSums) {
    __shared__ int sh[SCAN_B];
    int g = blockIdx.x * SCAN_B + threadIdx.x;
    int v = (g < N_NODES) ? counts[g] : 0;
    sh[threadIdx.x] = v;
    __syncthreads();
    for (int off = 1; off < SCAN_B; off <<= 1) {
        int t = (threadIdx.x >= off) ? sh[threadIdx.x - off] : 0;
        __syncthreads();
        sh[threadIdx.x] += t;
        __syncthreads();
    }
    int incl = sh[threadIdx.x];
    if (g < N_NODES) localScan[g] = incl - v;
    if (threadIdx.x == SCAN_B - 1) blockSums[blockIdx.x] = incl;
}

// ---- 2b. serial scan of 196 block sums ----
__global__ void k_scan_blocks(const int* __restrict__ blockSums,
                              int* __restrict__ blockBase) {
    if (threadIdx.x == 0 && blockIdx.x == 0) {
        int s = 0;
        for (int i = 0; i < N_SCAN_BLOCKS; i++) {
            blockBase[i] = s;
            s += blockSums[i];
        }
    }
}

// ---- 3a. rowStart + cursors ----
__global__ void k_cursor_init(const int* __restrict__ localScan,
                              const int* __restrict__ blockBase,
                              int* __restrict__ rowStart,
                              int* __restrict__ cursors) {
    int i = blockIdx.x * blockDim.x + threadIdx.x;
    if (i < N_NODES) {
        int v = localScan[i] + blockBase[i >> 9];
        rowStart[i] = v;
        cursors[i] = v;
    }
}

// ---- 3b. counting-sort edges by dst ----
__global__ void k_edge_scatter(const int* __restrict__ src,
                               const int* __restrict__ dst,
                               int* __restrict__ cursors,
                               int* __restrict__ sortedSrc) {
    int e = blockIdx.x * blockDim.x + threadIdx.x;
    if (e < N_EDGES) {
        int d = dst[e];
        int pos = atomicAdd(&cursors[d], 1);
        sortedSrc[pos] = src[e];
    }
}

// ---- 4. dis = rsqrt(deg + 1 self-loop) ----
__global__ void k_dis(const int* __restrict__ counts, float* __restrict__ dis) {
    int i = blockIdx.x * blockDim.x + threadIdx.x;
    if (i < N_NODES) dis[i] = rsqrtf((float)(counts[i] + 1));
}

// ---- 5a. W -> f32 ----
__global__ void k_wconv(const void* __restrict__ Wb, const int* __restrict__ flag,
                        float* __restrict__ Wf) {
    int i = blockIdx.x * blockDim.x + threadIdx.x;
    if (i >= F_IN * D_OUT) return;
    if (*flag) Wf[i] = ((const float*)Wb)[i];
    else       Wf[i] = bfbits2f(((const unsigned short*)Wb)[i]);
}

// ---- 5b. b -> f32 ----
__global__ void k_bconv(const void* __restrict__ bsrc, const int* __restrict__ flag,
                        float* __restrict__ bf) {
    int i = threadIdx.x;
    if (i < D_OUT) {
        if (*flag) bf[i] = ((const float*)bsrc)[i];
        else       bf[i] = bfbits2f(((const unsigned short*)bsrc)[i]);
    }
}

// ---- 6. y[row] = dis[row] * (X[row] @ W), stored bf16 ----
__global__ __launch_bounds__(256) void k_gemm_y(const void* __restrict__ feat,
                                                const float* __restrict__ Wf,
                                                const float* __restrict__ dis,
                                                const int* __restrict__ flag,
                                                unsigned short* __restrict__ y) {
    int row = blockIdx.x * blockDim.x + threadIdx.x;
    if (row >= N_NODES) return;
    float acc[D_OUT];
#pragma unroll
    for (int d = 0; d < D_OUT; d++) acc[d] = 0.f;

    if (*flag) {
        // f32 features (expected path)
        const float* fr = (const float*)feat + (size_t)row * F_IN;
        for (int k0 = 0; k0 < F_IN; k0 += 8) {
            float4 p0 = *reinterpret_cast<const float4*>(fr + k0);
            float4 p1 = *reinterpret_cast<const float4*>(fr + k0 + 4);
            float f[8] = {p0.x, p0.y, p0.z, p0.w, p1.x, p1.y, p1.z, p1.w};
#pragma unroll
            for (int j = 0; j < 8; j++) {
                float fv = f[j];
                const float* wr = Wf + (k0 + j) * D_OUT;
#pragma unroll
                for (int d = 0; d < D_OUT; d++) acc[d] = fmaf(fv, wr[d], acc[d]);
            }
        }
    } else {
        const unsigned short* fr = (const unsigned short*)feat + (size_t)row * F_IN;
        for (int k0 = 0; k0 < F_IN; k0 += 8) {
            uint4 pk = *reinterpret_cast<const uint4*>(fr + k0);
            unsigned u[4] = {pk.x, pk.y, pk.z, pk.w};
            float f[8];
#pragma unroll
            for (int j = 0; j < 4; j++) {
                f[2 * j]     = __uint_as_float(u[j] << 16);
                f[2 * j + 1] = __uint_as_float(u[j] & 0xffff0000u);
            }
#pragma unroll
            for (int j = 0; j < 8; j++) {
                float fv = f[j];
                const float* wr = Wf + (k0 + j) * D_OUT;
#pragma unroll
                for (int d = 0; d < D_OUT; d++) acc[d] = fmaf(fv, wr[d], acc[d]);
            }
        }
    }

    float dv = dis[row];
    unsigned out32[D_OUT / 2];
#pragma unroll
    for (int d = 0; d < D_OUT; d += 2) {
        out32[d >> 1] = (unsigned)f2bf_bits(acc[d] * dv) |
                        ((unsigned)f2bf_bits(acc[d + 1] * dv) << 16);
    }
    uint4* y4 = reinterpret_cast<uint4*>(y + (size_t)row * D_OUT);
#pragma unroll
    for (int q = 0; q < 8; q++)
        y4[q] = make_uint4(out32[4 * q], out32[4 * q + 1], out32[4 * q + 2], out32[4 * q + 3]);
}

// ---- 7. per-output-entry aggregation + gather: one wave per (batch,field) ----
// OUTPUT IS F32 (H1: reference output dtype is float32).
__global__ __launch_bounds__(256) void k_out(const int* __restrict__ x,
                                             const int* __restrict__ sortedSrc,
                                             const int* __restrict__ rowStart,
                                             const int* __restrict__ counts,
                                             const float* __restrict__ dis,
                                             const unsigned short* __restrict__ y,
                                             const float* __restrict__ bf,
                                             float* __restrict__ out) {
    int g = blockIdx.x * blockDim.x + threadIdx.x;
    int ent = g >> 6, lane = g & 63;
    if (ent >= N_ENTRIES) return;
    int node = x[ent];
    int start = rowStart[node];
    int cnt = counts[node];
    float self = bfbits2f(y[(size_t)node * D_OUT + lane]);
    float s0 = 0.f, s1 = 0.f, s2 = 0.f, s3 = 0.f;
    int e = 0;
    for (; e + 4 <= cnt; e += 4) {
        int i0 = sortedSrc[start + e];
        int i1 = sortedSrc[start + e + 1];
        int i2 = sortedSrc[start + e + 2];
        int i3 = sortedSrc[start + e + 3];
        s0 += bfbits2f(y[(size_t)i0 * D_OUT + lane]);
        s1 += bfbits2f(y[(size_t)i1 * D_OUT + lane]);
        s2 += bfbits2f(y[(size_t)i2 * D_OUT + lane]);
        s3 += bfbits2f(y[(size_t)i3 * D_OUT + lane]);
    }
    for (; e < cnt; e++) {
        int i0 = sortedSrc[start + e];
        s0 += bfbits2f(y[(size_t)i0 * D_OUT + lane]);
    }
    float sum = self + ((s0 + s1) + (s2 + s3));
    out[g] = dis[node] * sum + bf[lane];     // plain f32 store
}

extern "C" void kernel_launch(void* const* d_in, const int* in_sizes, int n_in,
                              void* d_out, int out_size, void* d_ws, size_t ws_size,
                              hipStream_t stream) {
    const void* feat      = d_in[0];
    const int* edge_index = (const int*)d_in[1];
    const void* Wb        = d_in[2];
    const void* bsrc      = d_in[3];
    const int* x          = (const int*)d_in[4];
    float* out            = (float*)d_out;

    const int* src = edge_index;
    const int* dst = edge_index + N_EDGES;

    // workspace layout (256B aligned) — total ~27.3 MB (proven in-bounds r2/r3)
    char* ws = (char*)d_ws;
    size_t off = 0;
    auto alloc = [&](size_t bytes) {
        size_t o = off;
        off = (off + bytes + 255) & ~(size_t)255;
        return o;
    };
    int*   flag      = (int*)  (ws + alloc(256));
    int*   counts    = (int*)  (ws + alloc((size_t)N_NODES * 4));
    int*   localScan = (int*)  (ws + alloc((size_t)N_NODES * 4));
    int*   rowStart  = (int*)  (ws + alloc((size_t)N_NODES * 4));
    int*   cursors   = (int*)  (ws + alloc((size_t)N_NODES * 4));
    float* dis       = (float*)(ws + alloc((size_t)N_NODES * 4));
    int*   blockSums = (int*)  (ws + alloc((size_t)N_SCAN_BLOCKS * 4));
    int*   blockBase = (int*)  (ws + alloc((size_t)N_SCAN_BLOCKS * 4));
    float* Wf        = (float*)(ws + alloc((size_t)F_IN * D_OUT * 4));
    float* bfArr     = (float*)(ws + alloc((size_t)D_OUT * 4));
    int*   sortedSrc = (int*)  (ws + alloc((size_t)N_EDGES * 4));
    unsigned short* y = (unsigned short*)(ws + alloc((size_t)N_NODES * D_OUT * 2));
    (void)ws_size; (void)in_sizes; (void)n_in; (void)out_size;

    hipMemsetAsync(counts, 0, (size_t)N_NODES * 4, stream);

    const int T = 256;
    k_detect<<<1, 256, 0, stream>>>((const unsigned*)feat, flag);
    k_count<<<(N_EDGES + T - 1) / T, T, 0, stream>>>(dst, counts);
    k_scan_local<<<N_SCAN_BLOCKS, SCAN_B, 0, stream>>>(counts, localScan, blockSums);
    k_scan_blocks<<<1, 64, 0, stream>>>(blockSums, blockBase);
    k_cursor_init<<<(N_NODES + T - 1) / T, T, 0, stream>>>(localScan, blockBase, rowStart, cursors);
    k_edge_scatter<<<(N_EDGES + T - 1) / T, T, 0, stream>>>(src, dst, cursors, sortedSrc);
    k_dis<<<(N_NODES + T - 1) / T, T, 0, stream>>>(counts, dis);
    k_wconv<<<(F_IN * D_OUT + T - 1) / T, T, 0, stream>>>(Wb, flag, Wf);
    k_bconv<<<1, 64, 0, stream>>>(bsrc, flag, bfArr);
    k_gemm_y<<<(N_NODES + T - 1) / T, T, 0, stream>>>(feat, Wf, dis, flag, y);
    k_out<<<((size_t)N_ENTRIES * 64 + T - 1) / T, T, 0, stream>>>(
        x, sortedSrc, rowStart, counts, dis, y, bfArr, out);
}

// Round 5
// 532.691 us; speedup vs baseline: 1.4569x; 1.4569x over previous
//
#include <hip/hip_runtime.h>
#include <hip/hip_bf16.h>

#define N_NODES 100000
#define N_EDGES 3200000
#define F_IN 256
#define D_OUT 64
#define BATCH 4096
#define N_FIELDS 20
#define N_ENTRIES (BATCH * N_FIELDS)          // 81920

#define NBUCKET 512
#define NPB 196                                // nodes per bucket (512*196 = 100352 >= 100000)
#define EPB 8192                               // edges per histogram/scatter block
#define NBLK ((N_EDGES + EPB - 1) / EPB)       // 391
#define BUCKET_CAP 8192                        // >> max bucket size (~6650 for uniform random)

static __device__ __forceinline__ float bfbits2f(unsigned short u) {
    return __uint_as_float((unsigned)u << 16);
}
static __device__ __forceinline__ unsigned short f2bf_bits(float x) {
    __hip_bfloat16 h = __float2bfloat16(x);
    return *reinterpret_cast<unsigned short*>(&h);
}

// ---- 0. dtype detector (insurance; r4 proved inputs are f32) ----
__global__ void k_detect(const unsigned* __restrict__ featw, int* __restrict__ flag) {
    __shared__ int cnt;
    if (threadIdx.x == 0) cnt = 0;
    __syncthreads();
    int hits = 0;
#pragma unroll
    for (int j = 0; j < 4; j++) {
        unsigned w = featw[threadIdx.x * 4 + j];
        int ex = (w >> 7) & 0xff;
        if (ex >= 90 && ex <= 160) hits++;
    }
    atomicAdd(&cnt, hits);
    __syncthreads();
    if (threadIdx.x == 0) *flag = (cnt >= 768) ? 0 /*bf16*/ : 1 /*f32*/;
}

// ---- 1. per-block bucket histogram: perBlockCnt[bucket*NBLK + blk] ----
__global__ __launch_bounds__(256) void k_hist(const int* __restrict__ dst,
                                              unsigned short* __restrict__ perBlockCnt) {
    __shared__ unsigned hist[NBUCKET];
    hist[threadIdx.x] = 0;
    hist[threadIdx.x + 256] = 0;
    __syncthreads();
    int base = blockIdx.x * EPB;
#pragma unroll 4
    for (int k = 0; k < EPB / 256; k++) {
        int e = base + k * 256 + threadIdx.x;
        if (e < N_EDGES) atomicAdd(&hist[(unsigned)dst[e] / NPB], 1u);
    }
    __syncthreads();
    perBlockCnt[(threadIdx.x) * NBLK + blockIdx.x] = (unsigned short)hist[threadIdx.x];
    perBlockCnt[(threadIdx.x + 256) * NBLK + blockIdx.x] = (unsigned short)hist[threadIdx.x + 256];
}

// ---- 2. column scan: perBlockCnt -> per-(bucket,block) exclusive offsets;
//         plus bucketBase[513] global scan ----
__global__ __launch_bounds__(512) void k_colscan(unsigned short* __restrict__ perBlockCnt,
                                                 int* __restrict__ bucketBase) {
    __shared__ unsigned tot[NBUCKET];
    int j = threadIdx.x;                 // bucket id
    unsigned s = 0;
    for (int blk = 0; blk < NBLK; blk++) {
        int idx = j * NBLK + blk;
        unsigned t = perBlockCnt[idx];
        perBlockCnt[idx] = (unsigned short)s;
        s += t;
    }
    tot[j] = s;
    __syncthreads();
    if (j == 0) {
        int run = 0;
        for (int b = 0; b < NBUCKET; b++) {
            bucketBase[b] = run;
            run += (int)tot[b];
        }
        bucketBase[NBUCKET] = run;       // == N_EDGES
    }
}

// ---- 3. scatter edges into bucket-grouped order (packed src | localDst<<17) ----
__global__ __launch_bounds__(256) void k_bucket_scatter(const int* __restrict__ src,
                                                        const int* __restrict__ dst,
                                                        const int* __restrict__ bucketBase,
                                                        const unsigned short* __restrict__ perBlockCnt,
                                                        unsigned* __restrict__ bucketData) {
    __shared__ unsigned slotBase[NBUCKET];
    slotBase[threadIdx.x] = (unsigned)bucketBase[threadIdx.x] +
                            (unsigned)perBlockCnt[threadIdx.x * NBLK + blockIdx.x];
    slotBase[threadIdx.x + 256] = (unsigned)bucketBase[threadIdx.x + 256] +
                                  (unsigned)perBlockCnt[(threadIdx.x + 256) * NBLK + blockIdx.x];
    __syncthreads();
    int base = blockIdx.x * EPB;
#pragma unroll 4
    for (int k = 0; k < EPB / 256; k++) {
        int e = base + k * 256 + threadIdx.x;
        if (e < N_EDGES) {
            unsigned s = (unsigned)src[e];
            unsigned d = (unsigned)dst[e];
            unsigned b = d / NPB;
            unsigned ld = d - b * NPB;           // < 196
            unsigned slot = atomicAdd(&slotBase[b], 1u);
            bucketData[slot] = s | (ld << 17);   // src < 2^17
        }
    }
}

// ---- 4. per-bucket CSR build: deg, dis, rowStart + in-place permute to
//         node-grouped src order (bucketData becomes sortedSrc) ----
__global__ __launch_bounds__(256) void k_bucket_csr(unsigned* __restrict__ bucketData,
                                                    const int* __restrict__ bucketBase,
                                                    int* __restrict__ rowStart,
                                                    float* __restrict__ dis) {
    __shared__ unsigned words[BUCKET_CAP];
    __shared__ unsigned srcsorted[BUCKET_CAP];
    __shared__ unsigned nodeCount[NPB];
    __shared__ unsigned nodeStart[NPB + 1];
    __shared__ unsigned cursor[NPB];

    int b = blockIdx.x;
    int base = bucketBase[b];
    int cnt = bucketBase[b + 1] - base;
    if (cnt > BUCKET_CAP) cnt = BUCKET_CAP;      // theoretical guard

    for (int j = threadIdx.x; j < NPB; j += 256) nodeCount[j] = 0;
    __syncthreads();

    for (int i = threadIdx.x; i < cnt; i += 256) {
        unsigned w = bucketData[base + i];
        words[i] = w;
        atomicAdd(&nodeCount[w >> 17], 1u);
    }
    __syncthreads();

    if (threadIdx.x == 0) {
        unsigned s = 0;
        for (int j = 0; j < NPB; j++) {
            nodeStart[j] = s;
            s += nodeCount[j];
        }
        nodeStart[NPB] = s;
    }
    __syncthreads();

    int firstNode = b * NPB;
    if (threadIdx.x < NPB) {
        int j = threadIdx.x;
        rowStart[firstNode + j] = base + (int)nodeStart[j];
        dis[firstNode + j] = rsqrtf((float)(nodeCount[j] + 1));
        cursor[j] = nodeStart[j];
    }
    __syncthreads();

    for (int i = threadIdx.x; i < cnt; i += 256) {
        unsigned w = words[i];
        unsigned slot = atomicAdd(&cursor[w >> 17], 1u);
        srcsorted[slot] = w & 0x1FFFFu;
    }
    __syncthreads();

    for (int i = threadIdx.x; i < cnt; i += 256)
        bucketData[base + i] = srcsorted[i];
}

// ---- 5a. W -> f32 ----
__global__ void k_wconv(const void* __restrict__ Wb, const int* __restrict__ flag,
                        float* __restrict__ Wf) {
    int i = blockIdx.x * blockDim.x + threadIdx.x;
    if (i >= F_IN * D_OUT) return;
    if (*flag) Wf[i] = ((const float*)Wb)[i];
    else       Wf[i] = bfbits2f(((const unsigned short*)Wb)[i]);
}

// ---- 5b. b -> f32 ----
__global__ void k_bconv(const void* __restrict__ bsrc, const int* __restrict__ flag,
                        float* __restrict__ bf) {
    int i = threadIdx.x;
    if (i < D_OUT) {
        if (*flag) bf[i] = ((const float*)bsrc)[i];
        else       bf[i] = bfbits2f(((const unsigned short*)bsrc)[i]);
    }
}

// ---- 6. y[row] = dis[row] * (X[row] @ W), stored bf16 ----
__global__ __launch_bounds__(256) void k_gemm_y(const void* __restrict__ feat,
                                                const float* __restrict__ Wf,
                                                const float* __restrict__ dis,
                                                const int* __restrict__ flag,
                                                unsigned short* __restrict__ y) {
    int row = blockIdx.x * blockDim.x + threadIdx.x;
    if (row >= N_NODES) return;
    float acc[D_OUT];
#pragma unroll
    for (int d = 0; d < D_OUT; d++) acc[d] = 0.f;

    if (*flag) {
        const float* fr = (const float*)feat + (size_t)row * F_IN;
        for (int k0 = 0; k0 < F_IN; k0 += 8) {
            float4 p0 = *reinterpret_cast<const float4*>(fr + k0);
            float4 p1 = *reinterpret_cast<const float4*>(fr + k0 + 4);
            float f[8] = {p0.x, p0.y, p0.z, p0.w, p1.x, p1.y, p1.z, p1.w};
#pragma unroll
            for (int j = 0; j < 8; j++) {
                float fv = f[j];
                const float* wr = Wf + (k0 + j) * D_OUT;
#pragma unroll
                for (int d = 0; d < D_OUT; d++) acc[d] = fmaf(fv, wr[d], acc[d]);
            }
        }
    } else {
        const unsigned short* fr = (const unsigned short*)feat + (size_t)row * F_IN;
        for (int k0 = 0; k0 < F_IN; k0 += 8) {
            uint4 pk = *reinterpret_cast<const uint4*>(fr + k0);
            unsigned u[4] = {pk.x, pk.y, pk.z, pk.w};
            float f[8];
#pragma unroll
            for (int j = 0; j < 4; j++) {
                f[2 * j]     = __uint_as_float(u[j] << 16);
                f[2 * j + 1] = __uint_as_float(u[j] & 0xffff0000u);
            }
#pragma unroll
            for (int j = 0; j < 8; j++) {
                float fv = f[j];
                const float* wr = Wf + (k0 + j) * D_OUT;
#pragma unroll
                for (int d = 0; d < D_OUT; d++) acc[d] = fmaf(fv, wr[d], acc[d]);
            }
        }
    }

    float dv = dis[row];
    unsigned out32[D_OUT / 2];
#pragma unroll
    for (int d = 0; d < D_OUT; d += 2) {
        out32[d >> 1] = (unsigned)f2bf_bits(acc[d] * dv) |
                        ((unsigned)f2bf_bits(acc[d + 1] * dv) << 16);
    }
    uint4* y4 = reinterpret_cast<uint4*>(y + (size_t)row * D_OUT);
#pragma unroll
    for (int q = 0; q < 8; q++)
        y4[q] = make_uint4(out32[4 * q], out32[4 * q + 1], out32[4 * q + 2], out32[4 * q + 3]);
}

// ---- 7. per-output-entry aggregation + gather (f32 out) ----
__global__ __launch_bounds__(256) void k_out(const int* __restrict__ x,
                                             const unsigned* __restrict__ sortedSrc,
                                             const int* __restrict__ rowStart,
                                             const float* __restrict__ dis,
                                             const unsigned short* __restrict__ y,
                                             const float* __restrict__ bf,
                                             float* __restrict__ out) {
    int g = blockIdx.x * blockDim.x + threadIdx.x;
    int ent = g >> 6, lane = g & 63;
    if (ent >= N_ENTRIES) return;
    int node = x[ent];
    int start = rowStart[node];
    int cnt = rowStart[node + 1] - start;
    float self = bfbits2f(y[(size_t)node * D_OUT + lane]);
    float s0 = 0.f, s1 = 0.f, s2 = 0.f, s3 = 0.f;
    int e = 0;
    for (; e + 4 <= cnt; e += 4) {
        unsigned i0 = sortedSrc[start + e];
        unsigned i1 = sortedSrc[start + e + 1];
        unsigned i2 = sortedSrc[start + e + 2];
        unsigned i3 = sortedSrc[start + e + 3];
        s0 += bfbits2f(y[(size_t)i0 * D_OUT + lane]);
        s1 += bfbits2f(y[(size_t)i1 * D_OUT + lane]);
        s2 += bfbits2f(y[(size_t)i2 * D_OUT + lane]);
        s3 += bfbits2f(y[(size_t)i3 * D_OUT + lane]);
    }
    for (; e < cnt; e++) {
        unsigned i0 = sortedSrc[start + e];
        s0 += bfbits2f(y[(size_t)i0 * D_OUT + lane]);
    }
    float sum = self + ((s0 + s1) + (s2 + s3));
    out[g] = dis[node] * sum + bf[lane];
}

extern "C" void kernel_launch(void* const* d_in, const int* in_sizes, int n_in,
                              void* d_out, int out_size, void* d_ws, size_t ws_size,
                              hipStream_t stream) {
    const void* feat      = d_in[0];
    const int* edge_index = (const int*)d_in[1];
    const void* Wb        = d_in[2];
    const void* bsrc      = d_in[3];
    const int* x          = (const int*)d_in[4];
    float* out            = (float*)d_out;

    const int* src = edge_index;
    const int* dst = edge_index + N_EDGES;

    // workspace layout (256B aligned) — total ~26.9 MB (< proven-safe 27.7 MB)
    char* ws = (char*)d_ws;
    size_t off = 0;
    auto alloc = [&](size_t bytes) {
        size_t o = off;
        off = (off + bytes + 255) & ~(size_t)255;
        return o;
    };
    int*   flag        = (int*)(ws + alloc(256));
    int*   bucketBase  = (int*)(ws + alloc((size_t)(NBUCKET + 1) * 4));
    unsigned short* perBlockCnt = (unsigned short*)(ws + alloc((size_t)NBUCKET * NBLK * 2));
    int*   rowStart    = (int*)(ws + alloc((size_t)(NBUCKET * NPB + 256) * 4));
    float* dis         = (float*)(ws + alloc((size_t)(NBUCKET * NPB + 256) * 4));
    float* Wf          = (float*)(ws + alloc((size_t)F_IN * D_OUT * 4));
    float* bfArr       = (float*)(ws + alloc((size_t)D_OUT * 4));
    unsigned* bucketData = (unsigned*)(ws + alloc((size_t)N_EDGES * 4));
    unsigned short* y  = (unsigned short*)(ws + alloc((size_t)N_NODES * D_OUT * 2));
    (void)ws_size; (void)in_sizes; (void)n_in; (void)out_size;

    const int T = 256;
    k_detect<<<1, 256, 0, stream>>>((const unsigned*)feat, flag);
    k_hist<<<NBLK, T, 0, stream>>>(dst, perBlockCnt);
    k_colscan<<<1, NBUCKET, 0, stream>>>(perBlockCnt, bucketBase);
    k_bucket_scatter<<<NBLK, T, 0, stream>>>(src, dst, bucketBase, perBlockCnt, bucketData);
    k_bucket_csr<<<NBUCKET, T, 0, stream>>>(bucketData, bucketBase, rowStart, dis);
    k_wconv<<<(F_IN * D_OUT + T - 1) / T, T, 0, stream>>>(Wb, flag, Wf);
    k_bconv<<<1, 64, 0, stream>>>(bsrc, flag, bfArr);
    k_gemm_y<<<(N_NODES + T - 1) / T, T, 0, stream>>>(feat, Wf, dis, flag, y);
    k_out<<<((size_t)N_ENTRIES * 64 + T - 1) / T, T, 0, stream>>>(
        x, bucketData, rowStart, dis, y, bfArr, out);
}

// Round 6
// 369.236 us; speedup vs baseline: 2.1018x; 1.4427x over previous
//
#include <hip/hip_runtime.h>
#include <hip/hip_bf16.h>

#define N_NODES 100000
#define N_EDGES 3200000
#define F_IN 256
#define D_OUT 64
#define BATCH 4096
#define N_FIELDS 20
#define N_ENTRIES (BATCH * N_FIELDS)          // 81920

#define NBUCKET 512
#define NPB 196                                // nodes per bucket
#define EPB 8192                               // edges per histogram/scatter block
#define NBLK ((N_EDGES + EPB - 1) / EPB)       // 391
#define BUCKET_CAP 8192

typedef short bf16x8 __attribute__((ext_vector_type(8)));
typedef float f32x4 __attribute__((ext_vector_type(4)));

static __device__ __forceinline__ float bfbits2f(unsigned short u) {
    return __uint_as_float((unsigned)u << 16);
}
static __device__ __forceinline__ unsigned short f2bf_bits(float x) {
    __hip_bfloat16 h = __float2bfloat16(x);
    return *reinterpret_cast<unsigned short*>(&h);
}

// ---- 1. per-block bucket histogram ----
__global__ __launch_bounds__(256) void k_hist(const int* __restrict__ dst,
                                              unsigned short* __restrict__ perBlockCnt) {
    __shared__ unsigned hist[NBUCKET];
    hist[threadIdx.x] = 0;
    hist[threadIdx.x + 256] = 0;
    __syncthreads();
    int base = blockIdx.x * EPB;
#pragma unroll 4
    for (int k = 0; k < EPB / 256; k++) {
        int e = base + k * 256 + threadIdx.x;
        if (e < N_EDGES) atomicAdd(&hist[(unsigned)dst[e] / NPB], 1u);
    }
    __syncthreads();
    perBlockCnt[(threadIdx.x) * NBLK + blockIdx.x] = (unsigned short)hist[threadIdx.x];
    perBlockCnt[(threadIdx.x + 256) * NBLK + blockIdx.x] = (unsigned short)hist[threadIdx.x + 256];
}

// ---- 2a. per-bucket wave scan across blocks (one wave per bucket) ----
__global__ __launch_bounds__(256) void k_colscan_w(unsigned short* __restrict__ perBlockCnt,
                                                   int* __restrict__ bucketTot) {
    int gw = (blockIdx.x * 256 + threadIdx.x) >> 6;   // bucket id
    int lane = threadIdx.x & 63;
    if (gw >= NBUCKET) return;
    unsigned running = 0;
    for (int c = 0; c < (NBLK + 63) / 64; c++) {
        int blk = c * 64 + lane;
        int idx = gw * NBLK + blk;
        unsigned v = (blk < NBLK) ? perBlockCnt[idx] : 0;
        unsigned orig = v;
#pragma unroll
        for (int d = 1; d < 64; d <<= 1) {
            unsigned t = __shfl_up(v, d, 64);
            if (lane >= d) v += t;
        }
        if (blk < NBLK) perBlockCnt[idx] = (unsigned short)(running + v - orig);
        running += __shfl(v, 63, 64);
    }
    if (lane == 0) bucketTot[gw] = (int)running;
}

// ---- 2b. scan 512 bucket totals -> bucketBase[513] ----
__global__ __launch_bounds__(512) void k_basescan(const int* __restrict__ bucketTot,
                                                  int* __restrict__ bucketBase) {
    __shared__ int sh[NBUCKET];
    int tid = threadIdx.x;
    int v = bucketTot[tid];
    sh[tid] = v;
    __syncthreads();
    for (int off = 1; off < NBUCKET; off <<= 1) {
        int t = (tid >= off) ? sh[tid - off] : 0;
        __syncthreads();
        sh[tid] += t;
        __syncthreads();
    }
    bucketBase[tid] = sh[tid] - v;
    if (tid == NBUCKET - 1) bucketBase[NBUCKET] = sh[NBUCKET - 1];
}

// ---- 3. scatter edges into bucket-grouped order (packed src | localDst<<17) ----
__global__ __launch_bounds__(256) void k_bucket_scatter(const int* __restrict__ src,
                                                        const int* __restrict__ dst,
                                                        const int* __restrict__ bucketBase,
                                                        const unsigned short* __restrict__ perBlockCnt,
                                                        unsigned* __restrict__ bucketData) {
    __shared__ unsigned slotBase[NBUCKET];
    slotBase[threadIdx.x] = (unsigned)bucketBase[threadIdx.x] +
                            (unsigned)perBlockCnt[threadIdx.x * NBLK + blockIdx.x];
    slotBase[threadIdx.x + 256] = (unsigned)bucketBase[threadIdx.x + 256] +
                                  (unsigned)perBlockCnt[(threadIdx.x + 256) * NBLK + blockIdx.x];
    __syncthreads();
    int base = blockIdx.x * EPB;
#pragma unroll 4
    for (int k = 0; k < EPB / 256; k++) {
        int e = base + k * 256 + threadIdx.x;
        if (e < N_EDGES) {
            unsigned s = (unsigned)src[e];
            unsigned d = (unsigned)dst[e];
            unsigned b = d / NPB;
            unsigned ld = d - b * NPB;
            unsigned slot = atomicAdd(&slotBase[b], 1u);
            bucketData[slot] = s | (ld << 17);
        }
    }
}

// ---- 4. per-bucket CSR build + in-place permute (parallel 256-thread scan) ----
__global__ __launch_bounds__(256) void k_bucket_csr(unsigned* __restrict__ bucketData,
                                                    const int* __restrict__ bucketBase,
                                                    int* __restrict__ rowStart,
                                                    float* __restrict__ dis) {
    __shared__ unsigned words[BUCKET_CAP];
    __shared__ unsigned srcsorted[BUCKET_CAP];
    __shared__ unsigned nodeCount[NPB];
    __shared__ unsigned sscan[256];
    __shared__ unsigned cursor[NPB];

    int b = blockIdx.x;
    int base = bucketBase[b];
    int cnt = bucketBase[b + 1] - base;
    if (cnt > BUCKET_CAP) cnt = BUCKET_CAP;
    int tid = threadIdx.x;

    for (int j = tid; j < NPB; j += 256) nodeCount[j] = 0;
    __syncthreads();

    for (int i = tid; i < cnt; i += 256) {
        unsigned w = bucketData[base + i];
        words[i] = w;
        atomicAdd(&nodeCount[w >> 17], 1u);
    }
    __syncthreads();

    unsigned v = (tid < NPB) ? nodeCount[tid] : 0;
    sscan[tid] = v;
    __syncthreads();
    for (int off = 1; off < 256; off <<= 1) {
        unsigned t = (tid >= off) ? sscan[tid - off] : 0;
        __syncthreads();
        sscan[tid] += t;
        __syncthreads();
    }

    int firstNode = b * NPB;
    if (tid < NPB) {
        unsigned excl = sscan[tid] - v;
        rowStart[firstNode + tid] = base + (int)excl;
        dis[firstNode + tid] = rsqrtf((float)(v + 1));
        cursor[tid] = excl;
    }
    __syncthreads();

    for (int i = tid; i < cnt; i += 256) {
        unsigned w = words[i];
        unsigned slot = atomicAdd(&cursor[w >> 17], 1u);
        srcsorted[slot] = w & 0x1FFFFu;
    }
    __syncthreads();

    for (int i = tid; i < cnt; i += 256)
        bucketData[base + i] = srcsorted[i];
}

// ---- 5a. W (f32, K x N) -> bf16 W^T (N x K) ----
__global__ void k_wtconv(const float* __restrict__ W, unsigned short* __restrict__ WTbf) {
    int i = blockIdx.x * blockDim.x + threadIdx.x;
    if (i >= D_OUT * F_IN) return;
    int n = i >> 8, k = i & 255;
    WTbf[i] = f2bf_bits(W[k * D_OUT + n]);
}

// ---- 5b. bias passthrough (f32) ----
__global__ void k_bconv(const float* __restrict__ bsrc, float* __restrict__ bf) {
    int i = threadIdx.x;
    if (i < D_OUT) bf[i] = bsrc[i];
}

// ---- 6. MFMA GEMM: y[row] = dis[row] * (X[row] @ W), bf16 out ----
// block = 4 waves, 64 rows; wave computes 16 rows x 64 cols via 4 n-tiles.
__global__ __launch_bounds__(256) void k_gemm_mfma(const float* __restrict__ feat,
                                                   const unsigned short* __restrict__ WTbf,
                                                   const float* __restrict__ dis,
                                                   unsigned short* __restrict__ y) {
    __shared__ unsigned short wt[64 * 264];    // W^T padded: [n][264]
    int tid = threadIdx.x;
    {
        int r = tid >> 2, seg = tid & 3;       // 64 rows x 4 segs of 64 bf16
        const uint4* gsrc = (const uint4*)(WTbf + r * 256 + seg * 64);
        uint4* ldst = (uint4*)&wt[r * 264 + seg * 64];
#pragma unroll
        for (int q = 0; q < 8; q++) ldst[q] = gsrc[q];
    }
    __syncthreads();

    int wave = tid >> 6, lane = tid & 63;
    int quad = lane >> 4, m = lane & 15;
    int rowT = blockIdx.x * 64 + wave * 16;
    int row = rowT + m;
    int rowC = (row < N_NODES) ? row : (N_NODES - 1);
    const float* fb = feat + (size_t)rowC * F_IN + quad * 8;

    f32x4 acc0 = {0.f, 0.f, 0.f, 0.f};
    f32x4 acc1 = acc0, acc2 = acc0, acc3 = acc0;

#pragma unroll
    for (int kk = 0; kk < 8; kk++) {
        float4 x0 = *(const float4*)(fb + kk * 32);
        float4 x1 = *(const float4*)(fb + kk * 32 + 4);
        bf16x8 a;
        a[0] = (short)f2bf_bits(x0.x); a[1] = (short)f2bf_bits(x0.y);
        a[2] = (short)f2bf_bits(x0.z); a[3] = (short)f2bf_bits(x0.w);
        a[4] = (short)f2bf_bits(x1.x); a[5] = (short)f2bf_bits(x1.y);
        a[6] = (short)f2bf_bits(x1.z); a[7] = (short)f2bf_bits(x1.w);
        int kbase = kk * 32 + quad * 8;
        bf16x8 b0 = *(const bf16x8*)&wt[(0 * 16 + m) * 264 + kbase];
        bf16x8 b1 = *(const bf16x8*)&wt[(1 * 16 + m) * 264 + kbase];
        bf16x8 b2 = *(const bf16x8*)&wt[(2 * 16 + m) * 264 + kbase];
        bf16x8 b3 = *(const bf16x8*)&wt[(3 * 16 + m) * 264 + kbase];
        acc0 = __builtin_amdgcn_mfma_f32_16x16x32_bf16(a, b0, acc0, 0, 0, 0);
        acc1 = __builtin_amdgcn_mfma_f32_16x16x32_bf16(a, b1, acc1, 0, 0, 0);
        acc2 = __builtin_amdgcn_mfma_f32_16x16x32_bf16(a, b2, acc2, 0, 0, 0);
        acc3 = __builtin_amdgcn_mfma_f32_16x16x32_bf16(a, b3, acc3, 0, 0, 0);
    }

    // D layout: m = quad*4 + r, n = lane&15 (per-tile)
    float dv[4];
#pragma unroll
    for (int r = 0; r < 4; r++) {
        int rr = rowT + quad * 4 + r;
        dv[r] = dis[(rr < N_NODES) ? rr : 0];
    }
#pragma unroll
    for (int r = 0; r < 4; r++) {
        int rr = rowT + quad * 4 + r;
        if (rr < N_NODES) {
            size_t o = (size_t)rr * D_OUT + m;
            y[o]      = f2bf_bits(acc0[r] * dv[r]);
            y[o + 16] = f2bf_bits(acc1[r] * dv[r]);
            y[o + 32] = f2bf_bits(acc2[r] * dv[r]);
            y[o + 48] = f2bf_bits(acc3[r] * dv[r]);
        }
    }
}

// ---- 7. per-output-entry aggregation + gather (f32 out) ----
__global__ __launch_bounds__(256) void k_out(const int* __restrict__ x,
                                             const unsigned* __restrict__ sortedSrc,
                                             const int* __restrict__ rowStart,
                                             const float* __restrict__ dis,
                                             const unsigned short* __restrict__ y,
                                             const float* __restrict__ bf,
                                             float* __restrict__ out) {
    int g = blockIdx.x * blockDim.x + threadIdx.x;
    int ent = g >> 6, lane = g & 63;
    if (ent >= N_ENTRIES) return;
    int node = x[ent];
    int start = rowStart[node];
    int cnt = rowStart[node + 1] - start;
    float self = bfbits2f(y[(size_t)node * D_OUT + lane]);
    float s0 = 0.f, s1 = 0.f, s2 = 0.f, s3 = 0.f;
    int e = 0;
    for (; e + 4 <= cnt; e += 4) {
        unsigned i0 = sortedSrc[start + e];
        unsigned i1 = sortedSrc[start + e + 1];
        unsigned i2 = sortedSrc[start + e + 2];
        unsigned i3 = sortedSrc[start + e + 3];
        s0 += bfbits2f(y[(size_t)i0 * D_OUT + lane]);
        s1 += bfbits2f(y[(size_t)i1 * D_OUT + lane]);
        s2 += bfbits2f(y[(size_t)i2 * D_OUT + lane]);
        s3 += bfbits2f(y[(size_t)i3 * D_OUT + lane]);
    }
    for (; e < cnt; e++) {
        unsigned i0 = sortedSrc[start + e];
        s0 += bfbits2f(y[(size_t)i0 * D_OUT + lane]);
    }
    float sum = self + ((s0 + s1) + (s2 + s3));
    out[g] = dis[node] * sum + bf[lane];
}

extern "C" void kernel_launch(void* const* d_in, const int* in_sizes, int n_in,
                              void* d_out, int out_size, void* d_ws, size_t ws_size,
                              hipStream_t stream) {
    const float* feat     = (const float*)d_in[0];
    const int* edge_index = (const int*)d_in[1];
    const float* W        = (const float*)d_in[2];
    const float* bsrc     = (const float*)d_in[3];
    const int* x          = (const int*)d_in[4];
    float* out            = (float*)d_out;

    const int* src = edge_index;
    const int* dst = edge_index + N_EDGES;

    // workspace layout (256B aligned) — ~26.8 MB (< proven-safe 27.7 MB)
    char* ws = (char*)d_ws;
    size_t off = 0;
    auto alloc = [&](size_t bytes) {
        size_t o = off;
        off = (off + bytes + 255) & ~(size_t)255;
        return o;
    };
    int* bucketBase = (int*)(ws + alloc((size_t)(NBUCKET + 1) * 4));
    int* bucketTot  = (int*)(ws + alloc((size_t)NBUCKET * 4));
    unsigned short* perBlockCnt = (unsigned short*)(ws + alloc((size_t)NBUCKET * NBLK * 2));
    int*   rowStart = (int*)(ws + alloc((size_t)(NBUCKET * NPB + 256) * 4));
    float* dis      = (float*)(ws + alloc((size_t)(NBUCKET * NPB + 256) * 4));
    unsigned short* WTbf = (unsigned short*)(ws + alloc((size_t)D_OUT * F_IN * 2));
    float* bfArr    = (float*)(ws + alloc((size_t)D_OUT * 4));
    unsigned* bucketData = (unsigned*)(ws + alloc((size_t)N_EDGES * 4));
    unsigned short* y = (unsigned short*)(ws + alloc((size_t)N_NODES * D_OUT * 2));
    (void)ws_size; (void)in_sizes; (void)n_in; (void)out_size;

    const int T = 256;
    k_hist<<<NBLK, T, 0, stream>>>(dst, perBlockCnt);
    k_colscan_w<<<(NBUCKET * 64 + T - 1) / T, T, 0, stream>>>(perBlockCnt, bucketTot);
    k_basescan<<<1, NBUCKET, 0, stream>>>(bucketTot, bucketBase);
    k_bucket_scatter<<<NBLK, T, 0, stream>>>(src, dst, bucketBase, perBlockCnt, bucketData);
    k_bucket_csr<<<NBUCKET, T, 0, stream>>>(bucketData, bucketBase, rowStart, dis);
    k_wtconv<<<(D_OUT * F_IN + T - 1) / T, T, 0, stream>>>(W, WTbf);
    k_bconv<<<1, 64, 0, stream>>>(bsrc, bfArr);
    k_gemm_mfma<<<(N_NODES + 63) / 64, T, 0, stream>>>(feat, WTbf, dis, y);
    k_out<<<((size_t)N_ENTRIES * 64 + T - 1) / T, T, 0, stream>>>(
        x, bucketData, rowStart, dis, y, bfArr, out);
}